// Round 6
// baseline (144.598 us; speedup 1.0000x reference)
//
#include <hip/hip_runtime.h>
#include <stdint.h>

#define KCAPS 10
#define OC    16
#define IC    256
#define HWSZ  36
#define PRIM  72
#define PD    8
#define EDIM  16

typedef short bf16x8 __attribute__((ext_vector_type(8)));
typedef float f32x4  __attribute__((ext_vector_type(4)));

// persistent prepped weights (recomputed every launch -> deterministic)
__device__ unsigned short g_whi[KCAPS * OC * IC];
__device__ unsigned short g_wlo[KCAPS * OC * IC];
__device__ float          g_wtsT[KCAPS * PRIM * EDIM * PD];   // [k][p][e][d]

// LDS map (44352 B):
//   [0, 19008)      xsh u32[36][132]  (bf16 [36][264])
//   [19008, 38016)  xsl u32[36][132]
//   [38016, 44352)  slack: GEMM A-fragment reads for discarded D-rows 36..47
//                   run past xsl (garbage, in-bounds, results discarded)
//   after GEMM barrier (xs dead):
//   [0, 23040)      caps f32[10][576]   (written by wave k, read by wave k only)
//   [23040, 28800)  b_s f32[720] | c_s f32[720]  (routing, after phase 2)
#define SMEM_BYTES 44352

__device__ __forceinline__ void bf_split(float v, unsigned short& hb, unsigned short& lb) {
    __bf16 h = (__bf16)v;
    hb = __builtin_bit_cast(unsigned short, h);
    __bf16 l = (__bf16)(v - (float)h);
    lb = __builtin_bit_cast(unsigned short, l);
}

__device__ __forceinline__ f32x4 mfma16(bf16x8 a, bf16x8 b, f32x4 c) {
    return __builtin_amdgcn_mfma_f32_16x16x32_bf16(a, b, c, 0, 0, 0);
}

__global__ __launch_bounds__(256)
void prep_kernel(const float* __restrict__ w, const float* __restrict__ wts) {
    int i = blockIdx.x * 256 + threadIdx.x;
    if (i < KCAPS * OC * IC) {
        unsigned short hb, lb;
        bf_split(w[i], hb, lb);
        g_whi[i] = hb;
        g_wlo[i] = lb;
    }
    if (i < KCAPS * PRIM * EDIM * PD) {           // 92160: [kp][e][d] <- [kp][d][e]
        int d = i & 7, e = (i >> 3) & 15, kp = i >> 7;
        g_wtsT[i] = wts[(size_t)kp * 128 + d * 16 + e];
    }
}

__global__ __launch_bounds__(640, 5)
void caps_one(const float* __restrict__ x, const float* __restrict__ conv_b,
              float* __restrict__ out) {
    extern __shared__ char smem[];
    uint32_t* xsh = (uint32_t*)smem;              // [36][132]
    uint32_t* xsl = xsh + 36 * 132;               // [36][132] (+slack beyond)
    const short* xshS = (const short*)xsh;
    const short* xslS = (const short*)xsl;
    float* caps_s = (float*)smem;                 // [10][576], overlays xs post-GEMM
    float* b_s    = (float*)smem + 5760;          // [720]
    float* c_s    = b_s + 720;                    // [720]

    const int t  = threadIdx.x;
    const int bb = blockIdx.x;
    const int k  = t >> 6;            // wave = capsule
    const int ln = t & 63;
    const int row = ln & 15;          // GEMM: tile row | routing: e
    const int g   = ln >> 4;          // GEMM: k-group  | routing: pr
    const int e   = row;
    const int pr  = g;

    // ---- phase 0: stage x transposed -> bf16 hi/lo [36 hw][264 c]
    {
        const float4* x4 = (const float4*)(x + (size_t)bb * (IC * HWSZ));
        for (int task = t; task < 1152; task += 640) {   // 128 c-pairs x 9 hw-quads
            int cp = task / 9, hq = task - cp * 9;
            float4 va = x4[(2 * cp) * 9 + hq];
            float4 vb = x4[(2 * cp + 1) * 9 + hq];
            int base = (4 * hq) * 132 + cp;
            unsigned short ha, la, hb, lb;
            bf_split(va.x, ha, la); bf_split(vb.x, hb, lb);
            xsh[base]       = (uint32_t)ha | ((uint32_t)hb << 16);
            xsl[base]       = (uint32_t)la | ((uint32_t)lb << 16);
            bf_split(va.y, ha, la); bf_split(vb.y, hb, lb);
            xsh[base + 132] = (uint32_t)ha | ((uint32_t)hb << 16);
            xsl[base + 132] = (uint32_t)la | ((uint32_t)lb << 16);
            bf_split(va.z, ha, la); bf_split(vb.z, hb, lb);
            xsh[base + 264] = (uint32_t)ha | ((uint32_t)hb << 16);
            xsl[base + 264] = (uint32_t)la | ((uint32_t)lb << 16);
            bf_split(va.w, ha, la); bf_split(vb.w, hb, lb);
            xsh[base + 396] = (uint32_t)ha | ((uint32_t)hb << 16);
            xsl[base + 396] = (uint32_t)la | ((uint32_t)lb << 16);
        }
    }
    __syncthreads();

    // ---- phase 1: GEMM, wave k computes its own 16x36 caps tile (bf16 3-pass)
    f32x4 acc[3] = {};
    #pragma unroll 2
    for (int kt = 0; kt < 8; ++kt) {
        int woff = (k * 16 + row) * 256 + kt * 32 + g * 8;
        bf16x8 bh = *(const bf16x8*)(g_whi + woff);
        bf16x8 bl = *(const bf16x8*)(g_wlo + woff);
        #pragma unroll
        for (int nt = 0; nt < 3; ++nt) {
            int o2 = (nt * 16 + row) * 264 + kt * 32 + g * 8;
            bf16x8 ah = *(const bf16x8*)(xshS + o2);
            bf16x8 al = *(const bf16x8*)(xslS + o2);
            acc[nt] = mfma16(ah, bh, acc[nt]);
            acc[nt] = mfma16(al, bh, acc[nt]);
            acc[nt] = mfma16(ah, bl, acc[nt]);
        }
    }
    __syncthreads();    // all xs reads done -> caps may overlay xs

    // ---- C-write: caps[k][o*36+hw]; wave k writes & reads only its own slice,
    //      so no barrier needed between this and phase 2.
    {
        float bias = conv_b[k * 16 + row];
        #pragma unroll
        for (int nt = 0; nt < 3; ++nt) {
            #pragma unroll
            for (int r = 0; r < 4; ++r) {
                int hw = nt * 16 + g * 4 + r;
                if (hw < HWSZ) caps_s[k * 576 + row * HWSZ + hw] = acc[nt][r] + bias;
            }
        }
    }

    // ---- phase 2: u in registers; lane (pr,e) holds u[k][4*p4+pr][e]
    float u_reg[18];
    float part1 = 0.f;
    #pragma unroll
    for (int p4 = 0; p4 < 18; ++p4) {
        int p = 4 * p4 + pr;
        const float4* cp4 = (const float4*)(caps_s + k * 576 + p * 8);   // broadcast over e-group
        float4 c0 = cp4[0], c1 = cp4[1];
        const float4* wq = (const float4*)(g_wtsT + ((size_t)(k * PRIM + p) * 16 + e) * 8);
        float4 w0 = wq[0], w1 = wq[1];
        float a = c0.x * w0.x;
        a = fmaf(c0.y, w0.y, a);
        a = fmaf(c0.z, w0.z, a);
        a = fmaf(c0.w, w0.w, a);
        a = fmaf(c1.x, w1.x, a);
        a = fmaf(c1.y, w1.y, a);
        a = fmaf(c1.z, w1.z, a);
        a = fmaf(c1.w, w1.w, a);
        u_reg[p4] = a;
        part1 += a;
    }

    // ---- routing iter 1: b=0 -> c=0.1 exactly; registers + shuffles, no barrier
    float v;
    {
        float s = part1 + __shfl_xor(part1, 16);
        s += __shfl_xor(s, 32);
        s *= 0.1f;
        float sq = s * s;
        sq += __shfl_xor(sq, 1); sq += __shfl_xor(sq, 2);
        sq += __shfl_xor(sq, 4); sq += __shfl_xor(sq, 8);
        float scale = (sq / (1.f + sq)) * rsqrtf(sq + 1e-8f);
        v = s * scale;
        #pragma unroll
        for (int p4 = 0; p4 < 18; ++p4) {
            float d = u_reg[p4] * v;
            d += __shfl_xor(d, 1); d += __shfl_xor(d, 2);
            d += __shfl_xor(d, 4); d += __shfl_xor(d, 8);
            if (e == 0) b_s[k * PRIM + 4 * p4 + pr] = d;    // b lives in LDS only
        }
    }

    // ---- routing iters 2,3
    #pragma unroll
    for (int it = 1; it < 3; ++it) {
        __syncthreads();              // b_s writes visible; prev c_s reads done
        if (t < PRIM) {               // softmax over k per primary
            float bv[KCAPS];
            float m = -1e30f;
            #pragma unroll
            for (int k2 = 0; k2 < KCAPS; ++k2) { bv[k2] = b_s[k2 * PRIM + t]; m = fmaxf(m, bv[k2]); }
            float sum = 0.f;
            #pragma unroll
            for (int k2 = 0; k2 < KCAPS; ++k2) { bv[k2] = __expf(bv[k2] - m); sum += bv[k2]; }
            float inv = 1.f / sum;
            #pragma unroll
            for (int k2 = 0; k2 < KCAPS; ++k2) c_s[k2 * PRIM + t] = bv[k2] * inv;
        }
        __syncthreads();              // c_s visible
        float partial = 0.f;
        #pragma unroll
        for (int p4 = 0; p4 < 18; ++p4)
            partial = fmaf(c_s[k * PRIM + 4 * p4 + pr], u_reg[p4], partial);
        float s = partial + __shfl_xor(partial, 16);
        s += __shfl_xor(s, 32);
        float sq = s * s;
        sq += __shfl_xor(sq, 1); sq += __shfl_xor(sq, 2);
        sq += __shfl_xor(sq, 4); sq += __shfl_xor(sq, 8);
        float scale = (sq / (1.f + sq)) * rsqrtf(sq + 1e-8f);
        v = s * scale;
        if (it < 2) {                 // agreement update (skip after final iter)
            #pragma unroll
            for (int p4 = 0; p4 < 18; ++p4) {
                float d = u_reg[p4] * v;
                d += __shfl_xor(d, 1); d += __shfl_xor(d, 2);
                d += __shfl_xor(d, 4); d += __shfl_xor(d, 8);
                if (e == 0) b_s[k * PRIM + 4 * p4 + pr] += d;
            }
        }
    }

    if (ln < 16) out[(size_t)bb * (KCAPS * EDIM) + k * 16 + ln] = v;
}

extern "C" void kernel_launch(void* const* d_in, const int* in_sizes, int n_in,
                              void* d_out, int out_size, void* d_ws, size_t ws_size,
                              hipStream_t stream) {
    const float* x  = (const float*)d_in[0];
    const float* cw = (const float*)d_in[1];
    const float* cb = (const float*)d_in[2];
    const float* wt = (const float*)d_in[3];
    float* out = (float*)d_out;
    const int B = in_sizes[0] / (IC * HWSZ);   // 2048

    hipLaunchKernelGGL(prep_kernel, dim3((KCAPS * PRIM * EDIM * PD + 255) / 256), dim3(256),
                       0, stream, cw, wt);
    hipLaunchKernelGGL(caps_one, dim3(B), dim3(640), SMEM_BYTES, stream, x, cb, out);
}

// Round 7
// 108.420 us; speedup vs baseline: 1.3337x; 1.3337x over previous
//
#include <hip/hip_runtime.h>
#include <stdint.h>

#define KCAPS 10
#define OC    16
#define IC    256
#define HWSZ  36
#define PRIM  72
#define PD    8
#define EDIM  16

typedef short bf16x8 __attribute__((ext_vector_type(8)));
typedef float f32x4  __attribute__((ext_vector_type(4)));

// persistent prepped weights (recomputed every launch -> deterministic)
__device__ unsigned short g_whi[KCAPS * OC * IC];
__device__ unsigned short g_wlo[KCAPS * OC * IC];
__device__ float          g_wtsT[KCAPS * PRIM * EDIM * PD];   // [k][p][e][d]

// LDS map (122112 B), 2 batch elements per block:
//   shorts [0,9504)      xs0h bf16[36][264]          bytes [0,19008)
//   shorts [9504,19008)  xs0l                        bytes [19008,38016)
//   shorts [19008,28512) xs1h                        bytes [38016,57024)
//   shorts [28512,38016) xs1l                        bytes [57024,76032)
//   f32 [19008,24768)    caps0 [10][576]             bytes [76032,99072)
//   f32 [24768,30528)    caps1 [10][576]             bytes [99072,122112)
//   GEMM A-fragment reads for discarded D-rows 36..47 over-run each xs half
//   (garbage, in-bounds, results discarded; caps not yet written then).
//   routing (xs dead): f32 b_s[2][720] at [0,1440) | c_s[2][720] at [1440,2880)
#define SMEM_BYTES 122112

__device__ __forceinline__ void bf_split(float v, unsigned short& hb, unsigned short& lb) {
    __bf16 h = (__bf16)v;
    hb = __builtin_bit_cast(unsigned short, h);
    __bf16 l = (__bf16)(v - (float)h);
    lb = __builtin_bit_cast(unsigned short, l);
}

__device__ __forceinline__ f32x4 mfma16(bf16x8 a, bf16x8 b, f32x4 c) {
    return __builtin_amdgcn_mfma_f32_16x16x32_bf16(a, b, c, 0, 0, 0);
}

__global__ __launch_bounds__(256)
void prep_kernel(const float* __restrict__ w, const float* __restrict__ wts) {
    int i = blockIdx.x * 256 + threadIdx.x;
    if (i < KCAPS * OC * IC) {
        unsigned short hb, lb;
        bf_split(w[i], hb, lb);
        g_whi[i] = hb;
        g_wlo[i] = lb;
    }
    if (i < KCAPS * PRIM * EDIM * PD) {           // 92160: [kp][e][d] <- [kp][d][e]
        int d = i & 7, e = (i >> 3) & 15, kp = i >> 7;
        g_wtsT[i] = wts[(size_t)kp * 128 + d * 16 + e];
    }
}

__global__ __launch_bounds__(640, 4)
void caps_two(const float* __restrict__ x, const float* __restrict__ conv_b,
              float* __restrict__ out) {
    extern __shared__ char smem[];
    uint32_t* xs_u  = (uint32_t*)smem;
    short*    xs_s  = (short*)smem;
    float*    sm_f  = (float*)smem;
    // short offsets: half hb2 -> hi at hb2*19008... (per-b region = 19008 shorts)
    // caps(b) float base:
    float* caps0 = sm_f + 19008;
    float* caps1 = sm_f + 24768;
    float* b_sm  = sm_f;            // [2][720] routing (xs dead)
    float* c_sm  = sm_f + 1440;     // [2][720]

    const int t  = threadIdx.x;
    const int bb = blockIdx.x;
    const int k  = t >> 6;            // wave = capsule
    const int ln = t & 63;
    const int row = ln & 15;          // GEMM: tile row | routing: e
    const int g   = ln >> 4;          // GEMM: k-group  | routing: pr
    const int e   = row;
    const int pr  = g;

    // ---- phase 0: stage BOTH batch elements, transposed bf16 hi/lo [36 hw][264 c]
    for (int task = t; task < 2304; task += 640) {
        int half = (task >= 1152) ? 1 : 0;
        int tt = task - half * 1152;
        int cp = tt / 9, hq = tt - cp * 9;
        const float4* x4 = (const float4*)(x + (size_t)(2 * bb + half) * (IC * HWSZ));
        float4 va = x4[(2 * cp) * 9 + hq];
        float4 vb = x4[(2 * cp + 1) * 9 + hq];
        uint32_t* xh = xs_u + half * 9504;          // u32 units
        uint32_t* xl = xh + 4752;
        int base = (4 * hq) * 132 + cp;
        unsigned short ha, la, hb, lb;
        bf_split(va.x, ha, la); bf_split(vb.x, hb, lb);
        xh[base]       = (uint32_t)ha | ((uint32_t)hb << 16);
        xl[base]       = (uint32_t)la | ((uint32_t)lb << 16);
        bf_split(va.y, ha, la); bf_split(vb.y, hb, lb);
        xh[base + 132] = (uint32_t)ha | ((uint32_t)hb << 16);
        xl[base + 132] = (uint32_t)la | ((uint32_t)lb << 16);
        bf_split(va.z, ha, la); bf_split(vb.z, hb, lb);
        xh[base + 264] = (uint32_t)ha | ((uint32_t)hb << 16);
        xl[base + 264] = (uint32_t)la | ((uint32_t)lb << 16);
        bf_split(va.w, ha, la); bf_split(vb.w, hb, lb);
        xh[base + 396] = (uint32_t)ha | ((uint32_t)hb << 16);
        xl[base + 396] = (uint32_t)la | ((uint32_t)lb << 16);
    }
    __syncthreads();

    // ---- phase 1: GEMM, wave k computes its 16x36 caps tile for BOTH b (bf16 3-pass)
    f32x4 acc0[3] = {}, acc1[3] = {};
    #pragma unroll 2
    for (int kt = 0; kt < 8; ++kt) {
        int woff = (k * 16 + row) * 256 + kt * 32 + g * 8;
        bf16x8 bh = *(const bf16x8*)(g_whi + woff);
        bf16x8 bl = *(const bf16x8*)(g_wlo + woff);
        #pragma unroll
        for (int nt = 0; nt < 3; ++nt) {
            int o2 = (nt * 16 + row) * 264 + kt * 32 + g * 8;
            bf16x8 ah0 = *(const bf16x8*)(xs_s + o2);
            bf16x8 al0 = *(const bf16x8*)(xs_s + 9504 + o2);
            bf16x8 ah1 = *(const bf16x8*)(xs_s + 19008 + o2);
            bf16x8 al1 = *(const bf16x8*)(xs_s + 28512 + o2);
            acc0[nt] = mfma16(ah0, bh, acc0[nt]);
            acc1[nt] = mfma16(ah1, bh, acc1[nt]);
            acc0[nt] = mfma16(al0, bh, acc0[nt]);
            acc1[nt] = mfma16(al1, bh, acc1[nt]);
            acc0[nt] = mfma16(ah0, bl, acc0[nt]);
            acc1[nt] = mfma16(ah1, bl, acc1[nt]);
        }
    }

    // ---- C-write: caps(b)[k][o*36+hw]; wave k writes/reads only its own slice -> no barrier
    {
        float bias = conv_b[k * 16 + row];
        #pragma unroll
        for (int nt = 0; nt < 3; ++nt) {
            #pragma unroll
            for (int r = 0; r < 4; ++r) {
                int hw = nt * 16 + g * 4 + r;
                if (hw < HWSZ) {
                    caps0[k * 576 + row * HWSZ + hw] = acc0[nt][r] + bias;
                    caps1[k * 576 + row * HWSZ + hw] = acc1[nt][r] + bias;
                }
            }
        }
    }

    // ---- phase 2: u in registers for both b; lane (pr,e) holds u[b][k][4*p4+pr][e]
    float u0[18], u1[18];
    float part0 = 0.f, part1 = 0.f;
    #pragma unroll
    for (int p4 = 0; p4 < 18; ++p4) {
        int p = 4 * p4 + pr;
        const float4* wq = (const float4*)(g_wtsT + ((size_t)(k * PRIM + p) * 16 + e) * 8);
        float4 w0 = wq[0], w1 = wq[1];                 // shared across both b
        const float4* ca = (const float4*)(caps0 + k * 576 + p * 8);
        const float4* cb = (const float4*)(caps1 + k * 576 + p * 8);
        float4 a0 = ca[0], a1 = ca[1];
        float4 b0 = cb[0], b1 = cb[1];
        float s0 = a0.x * w0.x, s1 = b0.x * w0.x;
        s0 = fmaf(a0.y, w0.y, s0); s1 = fmaf(b0.y, w0.y, s1);
        s0 = fmaf(a0.z, w0.z, s0); s1 = fmaf(b0.z, w0.z, s1);
        s0 = fmaf(a0.w, w0.w, s0); s1 = fmaf(b0.w, w0.w, s1);
        s0 = fmaf(a1.x, w1.x, s0); s1 = fmaf(b1.x, w1.x, s1);
        s0 = fmaf(a1.y, w1.y, s0); s1 = fmaf(b1.y, w1.y, s1);
        s0 = fmaf(a1.z, w1.z, s0); s1 = fmaf(b1.z, w1.z, s1);
        s0 = fmaf(a1.w, w1.w, s0); s1 = fmaf(b1.w, w1.w, s1);
        u0[p4] = s0; u1[p4] = s1;
        part0 += s0; part1 += s1;
    }
    __syncthreads();    // all xs reads done -> b_sm/c_sm may overlay xs

    // ---- routing iter 1: b=0 -> c=0.1 exactly; registers + shuffles
    float v0, v1;
    {
        float s0 = part0 + __shfl_xor(part0, 16);
        float s1 = part1 + __shfl_xor(part1, 16);
        s0 += __shfl_xor(s0, 32);  s1 += __shfl_xor(s1, 32);
        s0 *= 0.1f;  s1 *= 0.1f;
        float q0 = s0 * s0, q1 = s1 * s1;
        q0 += __shfl_xor(q0, 1); q1 += __shfl_xor(q1, 1);
        q0 += __shfl_xor(q0, 2); q1 += __shfl_xor(q1, 2);
        q0 += __shfl_xor(q0, 4); q1 += __shfl_xor(q1, 4);
        q0 += __shfl_xor(q0, 8); q1 += __shfl_xor(q1, 8);
        v0 = s0 * (q0 / (1.f + q0)) * rsqrtf(q0 + 1e-8f);
        v1 = s1 * (q1 / (1.f + q1)) * rsqrtf(q1 + 1e-8f);
        #pragma unroll
        for (int p4 = 0; p4 < 18; ++p4) {
            float d0 = u0[p4] * v0, d1 = u1[p4] * v1;
            d0 += __shfl_xor(d0, 1); d1 += __shfl_xor(d1, 1);
            d0 += __shfl_xor(d0, 2); d1 += __shfl_xor(d1, 2);
            d0 += __shfl_xor(d0, 4); d1 += __shfl_xor(d1, 4);
            d0 += __shfl_xor(d0, 8); d1 += __shfl_xor(d1, 8);
            if (e == 0) {
                b_sm[k * PRIM + 4 * p4 + pr] = d0;
                b_sm[720 + k * PRIM + 4 * p4 + pr] = d1;
            }
        }
    }

    // ---- routing iters 2,3: softmax for b0 on waves 0-1, b1 on waves 2-3 (concurrent)
    #pragma unroll
    for (int it = 1; it < 3; ++it) {
        __syncthreads();              // b_sm writes visible; prev c_sm reads done
        {
            int bsel = -1, tp = 0;
            if (t < PRIM)                        { bsel = 0; tp = t; }
            else if (t >= 128 && t < 128 + PRIM) { bsel = 1; tp = t - 128; }
            if (bsel >= 0) {
                const float* bp = b_sm + bsel * 720;
                float* cp = c_sm + bsel * 720;
                float bv[KCAPS];
                float m = -1e30f;
                #pragma unroll
                for (int k2 = 0; k2 < KCAPS; ++k2) { bv[k2] = bp[k2 * PRIM + tp]; m = fmaxf(m, bv[k2]); }
                float sum = 0.f;
                #pragma unroll
                for (int k2 = 0; k2 < KCAPS; ++k2) { bv[k2] = __expf(bv[k2] - m); sum += bv[k2]; }
                float inv = 1.f / sum;
                #pragma unroll
                for (int k2 = 0; k2 < KCAPS; ++k2) cp[k2 * PRIM + tp] = bv[k2] * inv;
            }
        }
        __syncthreads();              // c_sm visible
        float pa = 0.f, pb = 0.f;
        #pragma unroll
        for (int p4 = 0; p4 < 18; ++p4) {
            int p = 4 * p4 + pr;
            pa = fmaf(c_sm[k * PRIM + p], u0[p4], pa);
            pb = fmaf(c_sm[720 + k * PRIM + p], u1[p4], pb);
        }
        float s0 = pa + __shfl_xor(pa, 16);
        float s1 = pb + __shfl_xor(pb, 16);
        s0 += __shfl_xor(s0, 32);  s1 += __shfl_xor(s1, 32);
        float q0 = s0 * s0, q1 = s1 * s1;
        q0 += __shfl_xor(q0, 1); q1 += __shfl_xor(q1, 1);
        q0 += __shfl_xor(q0, 2); q1 += __shfl_xor(q1, 2);
        q0 += __shfl_xor(q0, 4); q1 += __shfl_xor(q1, 4);
        q0 += __shfl_xor(q0, 8); q1 += __shfl_xor(q1, 8);
        v0 = s0 * (q0 / (1.f + q0)) * rsqrtf(q0 + 1e-8f);
        v1 = s1 * (q1 / (1.f + q1)) * rsqrtf(q1 + 1e-8f);
        if (it < 2) {                 // agreement update (skip after final iter)
            #pragma unroll
            for (int p4 = 0; p4 < 18; ++p4) {
                float d0 = u0[p4] * v0, d1 = u1[p4] * v1;
                d0 += __shfl_xor(d0, 1); d1 += __shfl_xor(d1, 1);
                d0 += __shfl_xor(d0, 2); d1 += __shfl_xor(d1, 2);
                d0 += __shfl_xor(d0, 4); d1 += __shfl_xor(d1, 4);
                d0 += __shfl_xor(d0, 8); d1 += __shfl_xor(d1, 8);
                if (e == 0) {
                    b_sm[k * PRIM + 4 * p4 + pr] += d0;
                    b_sm[720 + k * PRIM + 4 * p4 + pr] += d1;
                }
            }
        }
    }

    if (ln < 16) {
        out[(size_t)(2 * bb) * (KCAPS * EDIM) + k * 16 + ln]     = v0;
        out[(size_t)(2 * bb + 1) * (KCAPS * EDIM) + k * 16 + ln] = v1;
    }
}

extern "C" void kernel_launch(void* const* d_in, const int* in_sizes, int n_in,
                              void* d_out, int out_size, void* d_ws, size_t ws_size,
                              hipStream_t stream) {
    const float* x  = (const float*)d_in[0];
    const float* cw = (const float*)d_in[1];
    const float* cb = (const float*)d_in[2];
    const float* wt = (const float*)d_in[3];
    float* out = (float*)d_out;
    const int B = in_sizes[0] / (IC * HWSZ);   // 2048

    hipLaunchKernelGGL(prep_kernel, dim3((KCAPS * PRIM * EDIM * PD + 255) / 256), dim3(256),
                       0, stream, cw, wt);

    hipFuncSetAttribute(reinterpret_cast<const void*>(&caps_two),
                        hipFuncAttributeMaxDynamicSharedMemorySize, SMEM_BYTES);
    hipLaunchKernelGGL(caps_two, dim3(B / 2), dim3(640), SMEM_BYTES, stream, x, cb, out);
}